// Round 3
// baseline (7176.354 us; speedup 1.0000x reference)
//
#include <hip/hip_runtime.h>

// GRU forward, B=64 S=512 I=512 H=1024. fp32 I/O, bf16 MFMA internals.
// Round 5: persistent fenceless kernel (round-4 sync machinery, verified),
// restructured to cut redundant uncached IC reads 2x:
//  - gate1 (256 blocks, 16 j each): computes BOTH z and r (Uz + Ur in its
//    64KB LDS). Publishes z (f32 coherent) + rh (bf16 coherent) + flagr.
//    Only consumer of the h-row -> hop1 readers 128->64 per bg.
//  - gate0 (128 blocks, 32 j each): Uh GEMM (64KB LDS) + h-update. Reads
//    rh-row + its 2KB z tile; no h-row read, no flagh wait.
//    hop2 readers 64->32 per bg.
//  - traffic 24 -> 12 MB/step; grid 384 x 64thr, 64KB LDS -> all co-resident.
//  - x@W on-the-fly, hidden under the opposite hop as before.

#define B_ 64
#define S_ 512
#define I_ 512
#define H_ 1024
#define HB_ (B_ * H_)

typedef short short8 __attribute__((ext_vector_type(8)));
typedef float floatx4 __attribute__((ext_vector_type(4)));

__device__ inline floatx4 mfma16(short8 a, short8 b, floatx4 c) {
    return __builtin_amdgcn_mfma_f32_16x16x32_bf16(a, b, c, 0, 0, 0);
}

// fp32 -> bf16 bits, round-to-nearest-even (inputs are finite)
__device__ inline short f2bf(float f) {
    union { float f; unsigned u; } v; v.f = f;
    unsigned r = (v.u + 0x7FFFu + ((v.u >> 16) & 1u)) >> 16;
    return (short)r;
}

// ---- bulk fp32 -> bf16 conversion, 8 elements/thread ----
__global__ __launch_bounds__(256) void cvt8k(const float* __restrict__ src,
                                             short* __restrict__ dst, int n8) {
    int i = blockIdx.x * 256 + threadIdx.x;
    if (i >= n8) return;
    const float4* p = reinterpret_cast<const float4*>(src) + (size_t)i * 2;
    float4 f0 = p[0], f1 = p[1];
    short8 o;
    o[0] = f2bf(f0.x); o[1] = f2bf(f0.y); o[2] = f2bf(f0.z); o[3] = f2bf(f0.w);
    o[4] = f2bf(f1.x); o[5] = f2bf(f1.y); o[6] = f2bf(f1.z); o[7] = f2bf(f1.w);
    reinterpret_cast<short8*>(dst)[i] = o;
}

// ---- init h state from h_0 and zero the sync flags ----
__global__ __launch_bounds__(256) void gru_init(const float* __restrict__ h0,
                                                float* __restrict__ h_f32,
                                                short* __restrict__ h_b,
                                                int* __restrict__ flags) {
    int i = blockIdx.x * 256 + threadIdx.x;
    if (i < 512) flags[i] = 0;
    if (i < HB_) {
        float v = h0[i];
        h_f32[i] = v;
        h_b[i] = f2bf(v);   // buffer 0 holds h(0)
    }
}

// A-fragment from fp32 x with on-the-fly bf16 conversion
__device__ inline short8 loadA_f32(const float* p) {
    const float4* q = reinterpret_cast<const float4*>(p);
    float4 f0 = q[0], f1 = q[1];
    short8 a;
    a[0] = f2bf(f0.x); a[1] = f2bf(f0.y); a[2] = f2bf(f0.z); a[3] = f2bf(f0.w);
    a[4] = f2bf(f1.x); a[5] = f2bf(f1.y); a[6] = f2bf(f1.z); a[7] = f2bf(f1.w);
    return a;
}

// lane i watches flags[i & mask]; exits when all watched flags >= target.
__device__ inline void wait_flags(const int* f, int mask, int target) {
    const int* p = f + (threadIdx.x & mask);
    while (__hip_atomic_load(p, __ATOMIC_RELAXED, __HIP_MEMORY_SCOPE_AGENT) < target)
        __builtin_amdgcn_s_sleep(1);
}

// 32 device-coherent 16B loads (bypass L1/L2 -> read at IC) with immediate
// offsets off one base, ONE vmcnt drain, then sched_barrier so the compiler
// cannot hoist consumers above the wait (guide rule #18).
__device__ inline void ld_frag32(const short* base, short8* f) {
    asm volatile(
        "global_load_dwordx4 %0, %16, off sc0 sc1\n\t"
        "global_load_dwordx4 %1, %16, off offset:64 sc0 sc1\n\t"
        "global_load_dwordx4 %2, %16, off offset:128 sc0 sc1\n\t"
        "global_load_dwordx4 %3, %16, off offset:192 sc0 sc1\n\t"
        "global_load_dwordx4 %4, %16, off offset:256 sc0 sc1\n\t"
        "global_load_dwordx4 %5, %16, off offset:320 sc0 sc1\n\t"
        "global_load_dwordx4 %6, %16, off offset:384 sc0 sc1\n\t"
        "global_load_dwordx4 %7, %16, off offset:448 sc0 sc1\n\t"
        "global_load_dwordx4 %8, %16, off offset:512 sc0 sc1\n\t"
        "global_load_dwordx4 %9, %16, off offset:576 sc0 sc1\n\t"
        "global_load_dwordx4 %10, %16, off offset:640 sc0 sc1\n\t"
        "global_load_dwordx4 %11, %16, off offset:704 sc0 sc1\n\t"
        "global_load_dwordx4 %12, %16, off offset:768 sc0 sc1\n\t"
        "global_load_dwordx4 %13, %16, off offset:832 sc0 sc1\n\t"
        "global_load_dwordx4 %14, %16, off offset:896 sc0 sc1\n\t"
        "global_load_dwordx4 %15, %16, off offset:960 sc0 sc1"
        : "=&v"(f[0]), "=&v"(f[1]), "=&v"(f[2]), "=&v"(f[3]),
          "=&v"(f[4]), "=&v"(f[5]), "=&v"(f[6]), "=&v"(f[7]),
          "=&v"(f[8]), "=&v"(f[9]), "=&v"(f[10]), "=&v"(f[11]),
          "=&v"(f[12]), "=&v"(f[13]), "=&v"(f[14]), "=&v"(f[15])
        : "v"(base)
        : "memory");
    asm volatile(
        "global_load_dwordx4 %0, %16, off offset:1024 sc0 sc1\n\t"
        "global_load_dwordx4 %1, %16, off offset:1088 sc0 sc1\n\t"
        "global_load_dwordx4 %2, %16, off offset:1152 sc0 sc1\n\t"
        "global_load_dwordx4 %3, %16, off offset:1216 sc0 sc1\n\t"
        "global_load_dwordx4 %4, %16, off offset:1280 sc0 sc1\n\t"
        "global_load_dwordx4 %5, %16, off offset:1344 sc0 sc1\n\t"
        "global_load_dwordx4 %6, %16, off offset:1408 sc0 sc1\n\t"
        "global_load_dwordx4 %7, %16, off offset:1472 sc0 sc1\n\t"
        "global_load_dwordx4 %8, %16, off offset:1536 sc0 sc1\n\t"
        "global_load_dwordx4 %9, %16, off offset:1600 sc0 sc1\n\t"
        "global_load_dwordx4 %10, %16, off offset:1664 sc0 sc1\n\t"
        "global_load_dwordx4 %11, %16, off offset:1728 sc0 sc1\n\t"
        "global_load_dwordx4 %12, %16, off offset:1792 sc0 sc1\n\t"
        "global_load_dwordx4 %13, %16, off offset:1856 sc0 sc1\n\t"
        "global_load_dwordx4 %14, %16, off offset:1920 sc0 sc1\n\t"
        "global_load_dwordx4 %15, %16, off offset:1984 sc0 sc1\n\t"
        "s_waitcnt vmcnt(0)"
        : "=&v"(f[16]), "=&v"(f[17]), "=&v"(f[18]), "=&v"(f[19]),
          "=&v"(f[20]), "=&v"(f[21]), "=&v"(f[22]), "=&v"(f[23]),
          "=&v"(f[24]), "=&v"(f[25]), "=&v"(f[26]), "=&v"(f[27]),
          "=&v"(f[28]), "=&v"(f[29]), "=&v"(f[30]), "=&v"(f[31])
        : "v"(base)
        : "memory");
    __builtin_amdgcn_sched_barrier(0);
}

// release publish: drain all outstanding stores, then relaxed flag store.
__device__ inline void publish(int* flag, int val, int lane) {
    asm volatile("s_waitcnt vmcnt(0)" ::: "memory");
    if (lane == 0)
        __hip_atomic_store(flag, val, __ATOMIC_RELAXED, __HIP_MEMORY_SCOPE_AGENT);
}

template <typename T>
__device__ inline void st_coh(T* p, T v) {
    __hip_atomic_store(p, v, __ATOMIC_RELAXED, __HIP_MEMORY_SCOPE_AGENT);
}

// ---- persistent GRU kernel: all S_ steps in one launch ----
// grid 384, 64 threads (1 wave), 64KB LDS each -> 2 blocks/CU, all resident.
//  blk <  256: gate1 = (bg = blk>>6, jg16 = blk&63)   z+r producer, 16 j
//  blk >= 256: gate0 = (bg = (blk-256)>>5, jg32 = &31) h-updater, 32 j
// MFMA 16x16x32 bf16 NT conventions (m89/m91-verified): A row = lane&15,
// k = quad*8+e; B row (= output col j) = lane&15; D: n = lane&15, m = quad*4+reg.
template <bool XB>
__global__ __launch_bounds__(64) void gru_persist(
    const float* __restrict__ x, const short* __restrict__ xb,
    const float* __restrict__ h0,
    const short* __restrict__ Wzb, const float* __restrict__ bz, const short* __restrict__ Uzb,
    const short* __restrict__ Wrb, const float* __restrict__ br, const short* __restrict__ Urb,
    const short* __restrict__ Whb, const float* __restrict__ bh, const short* __restrict__ Uhb,
    float* __restrict__ h_f32, short* __restrict__ h_b, short* __restrict__ rh,
    float* __restrict__ z_f32,
    int* __restrict__ flagh, int* __restrict__ flagr, float* __restrict__ out)
{
    __shared__ short8 Ulds[4096];   // 64 KiB

    const int blk  = blockIdx.x;
    const int lane = threadIdx.x;
    const int m16  = lane & 15, quad = lane >> 4;
    short8 frag[32];

    if (blk < 256) {
        // ================= gate1: z + r producer (16 j) =================
        const int bg = blk >> 6, jg = blk & 63;
        const int bBase = bg * 16, jBase = jg * 16;
        const int j = jBase + m16;

        // stage Uz -> [0..2048), Ur -> [2048..4096), 16B-chunk XOR swizzle
        for (int c = lane; c < 2048; c += 64) {
            int row = c >> 7, col = c & 127;
            int d = row * 128 + (col ^ (row & 7));
            Ulds[d]        = *(const short8*)(Uzb + (size_t)(jBase + row) * H_ + col * 8);
            Ulds[2048 + d] = *(const short8*)(Urb + (size_t)(jBase + row) * H_ + col * 8);
        }
        __syncthreads();

        const int ub  = m16 * 128 + (quad ^ (m16 & 3));
        const int itf = (m16 >> 2) & 1;
        const float bvz = bz[j], bvr = br[j];
        const short8* wzp = reinterpret_cast<const short8*>(Wzb + (size_t)j * I_) + quad;
        const short8* wrp = reinterpret_cast<const short8*>(Wrb + (size_t)j * I_) + quad;
        const int* fh = flagh + bg * 32;
        int* myfr = flagr + bg * 64 + jg;

        for (int t = 0; t < S_; ++t) {
            floatx4 az0 = {0,0,0,0}, az1 = {0,0,0,0};
            floatx4 ar0 = {0,0,0,0}, ar1 = {0,0,0,0};

            // ---- x@Wz, x@Wr: independent of h, runs before the wait ----
            const size_t xrow = ((size_t)(bBase + m16) * S_ + t) * I_;
            if (XB) {
                const short8* ax = reinterpret_cast<const short8*>(xb + xrow) + quad;
#pragma unroll
                for (int it = 0; it < I_ / 32; it += 2) {
                    short8 A0 = ax[it * 4], A1 = ax[(it + 1) * 4];
                    az0 = mfma16(A0, wzp[it * 4], az0);
                    ar0 = mfma16(A0, wrp[it * 4], ar0);
                    az1 = mfma16(A1, wzp[(it + 1) * 4], az1);
                    ar1 = mfma16(A1, wrp[(it + 1) * 4], ar1);
                }
            } else {
                const float* axf = x + xrow + quad * 8;
#pragma unroll
                for (int it = 0; it < I_ / 32; it += 2) {
                    short8 A0 = loadA_f32(axf + it * 32);
                    short8 A1 = loadA_f32(axf + (it + 1) * 32);
                    az0 = mfma16(A0, wzp[it * 4], az0);
                    ar0 = mfma16(A0, wrp[it * 4], ar0);
                    az1 = mfma16(A1, wzp[(it + 1) * 4], az1);
                    ar1 = mfma16(A1, wrp[(it + 1) * 4], ar1);
                }
            }

            // ---- wait for h(t) from the 32 gate0 producers ----
            wait_flags(fh, 31, t);

            // coherent h_f32 reads for the rh product (used in epilogue only)
            float hv[4];
#pragma unroll
            for (int r4 = 0; r4 < 4; ++r4)
                hv[r4] = __hip_atomic_load(h_f32 + (size_t)(bBase + quad * 4 + r4) * H_ + j,
                                           __ATOMIC_RELAXED, __HIP_MEMORY_SCOPE_AGENT);

            ld_frag32(h_b + (size_t)(t & 1) * HB_ + (size_t)(bBase + m16) * H_ + quad * 8, frag);
#pragma unroll
            for (int it = 0; it < H_ / 32; it += 2) {
                short8 F0 = frag[it], F1 = frag[it + 1];
                az0 = mfma16(F0, Ulds[ub + ((it ^ itf) << 2)], az0);
                ar0 = mfma16(F0, Ulds[2048 + ub + ((it ^ itf) << 2)], ar0);
                az1 = mfma16(F1, Ulds[ub + (((it + 1) ^ itf) << 2)], az1);
                ar1 = mfma16(F1, Ulds[2048 + ub + (((it + 1) ^ itf) << 2)], ar1);
            }
            floatx4 az = az0 + az1, ar = ar0 + ar1;

#pragma unroll
            for (int r4 = 0; r4 < 4; ++r4) {
                size_t idx = (size_t)(bBase + quad * 4 + r4) * H_ + j;
                st_coh(z_f32 + idx, 1.f / (1.f + __expf(-(az[r4] + bvz))));
                float g = 1.f / (1.f + __expf(-(ar[r4] + bvr)));
                st_coh(rh + idx, f2bf(g * hv[r4]));
            }
            publish(myfr, t + 1, lane);
        }
    } else {
        // ================= gate0: h-updater (32 j) =================
        const int idx0 = blk - 256;
        const int bg = idx0 >> 5, jg = idx0 & 31;
        const int bBase = bg * 16, jBase = jg * 32;
        const int j0 = jBase + m16, j1 = j0 + 16;

        // stage Uh (32 rows) swizzled; rows 16..31 land at +2048
        for (int c = lane; c < 4096; c += 64) {
            int row = c >> 7, col = c & 127;
            Ulds[row * 128 + (col ^ (row & 7))] =
                *(const short8*)(Uhb + (size_t)(jBase + row) * H_ + col * 8);
        }
        __syncthreads();

        const int ub  = m16 * 128 + (quad ^ (m16 & 3));
        const int itf = (m16 >> 2) & 1;
        const float bv0 = bh[j0], bv1 = bh[j1];
        const short8* wh0 = reinterpret_cast<const short8*>(Whb + (size_t)j0 * I_) + quad;
        const short8* wh1 = reinterpret_cast<const short8*>(Whb + (size_t)j1 * I_) + quad;
        const int* fr = flagr + bg * 64;
        int* myfh = flagh + bg * 32 + jg;

        // f32 master copy of this block's stationary 16b x 32j h tile
        float hreg[2][4];
#pragma unroll
        for (int r4 = 0; r4 < 4; ++r4) {
            hreg[0][r4] = h0[(size_t)(bBase + quad * 4 + r4) * H_ + j0];
            hreg[1][r4] = h0[(size_t)(bBase + quad * 4 + r4) * H_ + j1];
        }

        for (int t = 0; t < S_; ++t) {
            floatx4 c00 = {0,0,0,0}, c01 = {0,0,0,0};
            floatx4 c10 = {0,0,0,0}, c11 = {0,0,0,0};

            // ---- x@Wh for both 16-col tiles: runs before the wait ----
            const size_t xrow = ((size_t)(bBase + m16) * S_ + t) * I_;
            if (XB) {
                const short8* ax = reinterpret_cast<const short8*>(xb + xrow) + quad;
#pragma unroll
                for (int it = 0; it < I_ / 32; it += 2) {
                    short8 A0 = ax[it * 4], A1 = ax[(it + 1) * 4];
                    c00 = mfma16(A0, wh0[it * 4], c00);
                    c10 = mfma16(A0, wh1[it * 4], c10);
                    c01 = mfma16(A1, wh0[(it + 1) * 4], c01);
                    c11 = mfma16(A1, wh1[(it + 1) * 4], c11);
                }
            } else {
                const float* axf = x + xrow + quad * 8;
#pragma unroll
                for (int it = 0; it < I_ / 32; it += 2) {
                    short8 A0 = loadA_f32(axf + it * 32);
                    short8 A1 = loadA_f32(axf + (it + 1) * 32);
                    c00 = mfma16(A0, wh0[it * 4], c00);
                    c10 = mfma16(A0, wh1[it * 4], c10);
                    c01 = mfma16(A1, wh0[(it + 1) * 4], c01);
                    c11 = mfma16(A1, wh1[(it + 1) * 4], c11);
                }
            }

            // ---- wait for rh(t)/z(t) from the 64 gate1 producers ----
            wait_flags(fr, 63, t + 1);

            // coherent z-tile loads (epilogue use; overlap the GEMM)
            float zv[2][4];
#pragma unroll
            for (int r4 = 0; r4 < 4; ++r4) {
                size_t row = (size_t)(bBase + quad * 4 + r4) * H_;
                zv[0][r4] = __hip_atomic_load(z_f32 + row + j0,
                                              __ATOMIC_RELAXED, __HIP_MEMORY_SCOPE_AGENT);
                zv[1][r4] = __hip_atomic_load(z_f32 + row + j1,
                                              __ATOMIC_RELAXED, __HIP_MEMORY_SCOPE_AGENT);
            }

            ld_frag32(rh + (size_t)(bBase + m16) * H_ + quad * 8, frag);
#pragma unroll
            for (int it = 0; it < H_ / 32; it += 2) {
                short8 F0 = frag[it], F1 = frag[it + 1];
                c00 = mfma16(F0, Ulds[ub + ((it ^ itf) << 2)], c00);
                c10 = mfma16(F0, Ulds[2048 + ub + ((it ^ itf) << 2)], c10);
                c01 = mfma16(F1, Ulds[ub + (((it + 1) ^ itf) << 2)], c01);
                c11 = mfma16(F1, Ulds[2048 + ub + (((it + 1) ^ itf) << 2)], c11);
            }
            floatx4 acc0 = c00 + c01, acc1 = c10 + c11;

            // ---- h update epilogue, both column tiles ----
#pragma unroll
            for (int n = 0; n < 2; ++n) {
                floatx4 acc = n ? acc1 : acc0;
                float bv = n ? bv1 : bv0;
                int jj = n ? j1 : j0;
#pragma unroll
                for (int r4 = 0; r4 < 4; ++r4) {
                    int b = bBase + quad * 4 + r4;
                    size_t idx = (size_t)b * H_ + jj;
                    float hh = tanhf(acc[r4] + bv);
                    float hn = fmaf(zv[n][r4], hh - hreg[n][r4], hreg[n][r4]);
                    hreg[n][r4] = hn;
                    st_coh(h_f32 + idx, hn);
                    st_coh(h_b + (size_t)((t + 1) & 1) * HB_ + idx, f2bf(hn));
                    out[(size_t)b * (S_ * H_) + (size_t)t * H_ + jj] = hn;
                    if (t == S_ - 1) out[(size_t)(B_ * S_ * H_) + idx] = hn;
                }
            }
            publish(myfh, t + 1, lane);
        }
    }
}

extern "C" void kernel_launch(void* const* d_in, const int* in_sizes, int n_in,
                              void* d_out, int out_size, void* d_ws, size_t ws_size,
                              hipStream_t stream) {
    const float* x  = (const float*)d_in[0];
    const float* h0 = (const float*)d_in[1];
    const float* Wz = (const float*)d_in[2];
    const float* bz = (const float*)d_in[3];
    const float* Uz = (const float*)d_in[4];
    const float* Wr = (const float*)d_in[5];
    const float* br = (const float*)d_in[6];
    const float* Ur = (const float*)d_in[7];
    const float* Wh = (const float*)d_in[8];
    const float* bh = (const float*)d_in[9];
    const float* Uh = (const float*)d_in[10];
    float* out = (float*)d_out;

    const int WI = H_ * I_;                  // 524288 elems per W
    const int UU = H_ * H_;                  // 1048576 elems per U
    const size_t XN = (size_t)B_ * S_ * I_;  // 16777216 elems

    // ws layout: h_f32 | z_f32 | h_bf16[2] | rh | flags[512] | W bf16 x3 | U bf16 x3 | [x_b]
    char* w = (char*)d_ws;
    float* h_f32 = (float*)w;            w += (size_t)HB_ * 4;
    float* z_f32 = (float*)w;            w += (size_t)HB_ * 4;
    short* h_b   = (short*)w;            w += (size_t)HB_ * 2 * 2;   // double buffer
    short* rhb   = (short*)w;            w += (size_t)HB_ * 2;
    int*   flags = (int*)w;              w += 512 * 4;
    short* Wzb   = (short*)w;            w += (size_t)WI * 2;
    short* Wrb   = (short*)w;            w += (size_t)WI * 2;
    short* Whb   = (short*)w;            w += (size_t)WI * 2;
    short* Uzb   = (short*)w;            w += (size_t)UU * 2;
    short* Urb   = (short*)w;            w += (size_t)UU * 2;
    short* Uhb   = (short*)w;            w += (size_t)UU * 2;
    size_t base_need = (size_t)(w - (char*)d_ws);
    bool XB = ws_size >= base_need + XN * 2;
    short* xb = (short*)w;

    int* flagh = flags;          // [4][32]  gate0 -> gate1
    int* flagr = flags + 128;    // [4][64]  gate1 -> gate0

    gru_init<<<dim3(HB_ / 256), 256, 0, stream>>>(h0, h_f32, h_b, flags);
    cvt8k<<<dim3(WI / 8 / 256), 256, 0, stream>>>(Wz, Wzb, WI / 8);
    cvt8k<<<dim3(WI / 8 / 256), 256, 0, stream>>>(Wr, Wrb, WI / 8);
    cvt8k<<<dim3(WI / 8 / 256), 256, 0, stream>>>(Wh, Whb, WI / 8);
    cvt8k<<<dim3(UU / 8 / 256), 256, 0, stream>>>(Uz, Uzb, UU / 8);
    cvt8k<<<dim3(UU / 8 / 256), 256, 0, stream>>>(Ur, Urb, UU / 8);
    cvt8k<<<dim3(UU / 8 / 256), 256, 0, stream>>>(Uh, Uhb, UU / 8);
    if (XB)
        cvt8k<<<dim3((int)(XN / 8 / 256)), 256, 0, stream>>>(x, xb, (int)(XN / 8));

    if (XB)
        gru_persist<true><<<dim3(384), 64, 0, stream>>>(
            x, xb, h0, Wzb, bz, Uzb, Wrb, br, Urb, Whb, bh, Uhb,
            h_f32, h_b, rhb, z_f32, flagh, flagr, out);
    else
        gru_persist<false><<<dim3(384), 64, 0, stream>>>(
            x, xb, h0, Wzb, bz, Uzb, Wrb, br, Urb, Whb, bh, Uhb,
            h_f32, h_b, rhb, z_f32, flagh, flagr, out);
}